// Round 7
// baseline (201.113 us; speedup 1.0000x reference)
//
#include <hip/hip_runtime.h>
#include <math.h>

#define Bn 8
#define Cc 512
#define HW 1024
#define HEADS 8
#define HD 64
#define GROUPS 32
#define CPG 16
#define EPS 1e-5f

typedef float f32x4 __attribute__((ext_vector_type(4)));
typedef __bf16 bf16x8 __attribute__((ext_vector_type(8)));
typedef __bf16 bf16x4 __attribute__((ext_vector_type(4)));
typedef short s16x4 __attribute__((ext_vector_type(4)));

__device__ __forceinline__ void async16(const __bf16* g, __bf16* l) {
    __builtin_amdgcn_global_load_lds((const __attribute__((address_space(1))) unsigned int*)g,
                                     (__attribute__((address_space(3))) unsigned int*)l, 16, 0, 0);
}

__device__ __forceinline__ f32x4 mfma16(bf16x4 a, bf16x4 b, f32x4 c) {
    return __builtin_amdgcn_mfma_f32_16x16x16bf16_1k(
        __builtin_bit_cast(s16x4, a), __builtin_bit_cast(s16x4, b), c, 0, 0, 0);
}

// ---------------- fp32 -> bf16 weight conversion (both weights, one launch) ----------------
__global__ void conv_kernel(const float* __restrict__ a, __bf16* __restrict__ da, int na4,
                            const float* __restrict__ b, __bf16* __restrict__ db, int nb4) {
    int i = blockIdx.x * 256 + threadIdx.x;
    if (i < na4) {
        float4 v = ((const float4*)a)[i];
        bf16x4 o = { (__bf16)v.x, (__bf16)v.y, (__bf16)v.z, (__bf16)v.w };
        ((bf16x4*)da)[i] = o;
    } else {
        int j = i - na4;
        if (j < nb4) {
            float4 v = ((const float4*)b)[j];
            bf16x4 o = { (__bf16)v.x, (__bf16)v.y, (__bf16)v.z, (__bf16)v.w };
            ((bf16x4*)db)[j] = o;
        }
    }
}

// ---------------- GroupNorm stats: one block per (b, group) ----------------
__global__ __launch_bounds__(256) void gn_stats(const float* __restrict__ x,
                                                float* __restrict__ gstats) {
    int bg = blockIdx.x;
    int b = bg >> 5, g = bg & 31;
    const float* xp = x + ((size_t)b * Cc + g * CPG) * HW;
    int tid = threadIdx.x;
    float s = 0.f, ss = 0.f;
    for (int i = tid; i < CPG * HW; i += 256) {
        float v = xp[i];
        s += v; ss += v * v;
    }
    __shared__ float red0[4], red1[4];
    for (int off = 32; off > 0; off >>= 1) {
        s  += __shfl_down(s, off);
        ss += __shfl_down(ss, off);
    }
    int wave = tid >> 6, lane = tid & 63;
    if (lane == 0) { red0[wave] = s; red1[wave] = ss; }
    __syncthreads();
    if (tid == 0) {
        float S  = red0[0] + red0[1] + red0[2] + red0[3];
        float SS = red1[0] + red1[1] + red1[2] + red1[3];
        float mean = S / (float)(CPG * HW);
        float var  = SS / (float)(CPG * HW) - mean * mean;
        gstats[bg * 2]     = mean;
        gstats[bg * 2 + 1] = rsqrtf(var + EPS);
    }
}

// ---------------- GroupNorm apply -> hnT[b][n][c], fully coalesced writes ----------------
__global__ __launch_bounds__(256) void gn_apply(const float* __restrict__ x,
                                                const float* __restrict__ gamma,
                                                const float* __restrict__ beta,
                                                const float* __restrict__ gstats,
                                                __bf16* __restrict__ hnT) {
    int b = blockIdx.y, n0 = blockIdx.x * 32;
    __shared__ __align__(16) __bf16 T[32 * 520];
    __shared__ float gl[512], bl[512], sm[32], sr[32];
    int tid = threadIdx.x;
    if (tid < 32) {
        sm[tid] = gstats[(b * 32 + tid) * 2];
        sr[tid] = gstats[(b * 32 + tid) * 2 + 1];
    }
    for (int i = tid; i < 512; i += 256) { gl[i] = gamma[i]; bl[i] = beta[i]; }
    __syncthreads();
    const float* xb = x + (size_t)b * Cc * HW + n0;
    for (int i = tid; i < 16384; i += 256) {
        int c = i >> 5, n = i & 31;
        float v = xb[(size_t)c * HW + n];
        int g = c >> 4;
        T[n * 520 + c] = (__bf16)((v - sm[g]) * sr[g] * gl[c] + bl[c]);
    }
    __syncthreads();
    __bf16* hb = hnT + ((size_t)b * HW + n0) * Cc;
    for (int j = tid; j < 2048; j += 256) {
        int n = j >> 6, ch = j & 63;
        *(bf16x8*)&hb[(size_t)n * Cc + ch * 8] = *(const bf16x8*)&T[n * 520 + ch * 8];
    }
}

// ---------------- MFMA GEMM, double-buffered staging ----------------
// D[m][n] = sum_k P[m][k] * Q[n][k]. Tile MT*32 x 128, 4 waves 2x2.
template<int MT, bool BIAS_COL, bool RESID_F32>
__global__ __launch_bounds__(256) void gemm_mfma(
    const __bf16* __restrict__ Pm, const __bf16* __restrict__ Qm,
    const float* __restrict__ bias, const float* __restrict__ resid,
    void* __restrict__ outv, size_t pStride, size_t qStride, size_t oStride, int oN,
    float scaleLo, int loCols) {
    __shared__ __align__(16) __bf16 As[2][MT * 32 * 64];
    __shared__ __align__(16) __bf16 Bs[2][128 * 64];
    int tid = threadIdx.x;
    int wv = tid >> 6, lane = tid & 63, ln = lane & 15, quad = lane >> 4;
    int b = blockIdx.z;
    int bm = blockIdx.y * (MT * 32), bn = blockIdx.x * 128;
    const __bf16* Pb = Pm + (size_t)b * pStride;
    const __bf16* Qb = Qm + (size_t)b * qStride;
    int wm = (wv >> 1) * (MT * 16), wn = (wv & 1) * 64;

    f32x4 acc[MT][4];
    #pragma unroll
    for (int i = 0; i < MT; ++i)
        #pragma unroll
        for (int j = 0; j < 4; ++j) acc[i][j] = (f32x4){0.f, 0.f, 0.f, 0.f};

    // staging lambda: tile k0 -> buffer bu
    auto stage = [&](int k0, int bu) {
        #pragma unroll
        for (int u = 0; u < MT; ++u) {
            int idx = u * 256 + tid;
            int r = idx >> 3, lc = idx & 7;
            int cg = lc ^ (r & 7);
            async16(Pb + (size_t)(bm + r) * 512 + k0 + cg * 8, &As[bu][r * 64 + lc * 8]);
        }
        #pragma unroll
        for (int u = 0; u < 4; ++u) {
            int idx = u * 256 + tid;
            int r = idx >> 3, lc = idx & 7;
            int cg = lc ^ (r & 7);
            async16(Qb + (size_t)(bn + r) * 512 + k0 + cg * 8, &Bs[bu][r * 64 + lc * 8]);
        }
    };

    stage(0, 0);
    for (int t = 0; t < 8; ++t) {
        int cur = t & 1;
        __syncthreads();                    // buf[cur] ready; prev compute done
        if (t < 7) stage((t + 1) * 64, cur ^ 1);   // prefetch overlaps compute below
        bf16x8 af[MT][2], bff[4][2];
        #pragma unroll
        for (int mt = 0; mt < MT; ++mt) {
            int row = wm + mt * 16 + ln;
            #pragma unroll
            for (int h = 0; h < 2; ++h) {
                int cc = (h * 4 + quad) ^ (ln & 7);
                af[mt][h] = *(const bf16x8*)&As[cur][row * 64 + cc * 8];
            }
        }
        #pragma unroll
        for (int nt = 0; nt < 4; ++nt) {
            int row = wn + nt * 16 + ln;
            #pragma unroll
            for (int h = 0; h < 2; ++h) {
                int cc = (h * 4 + quad) ^ (ln & 7);
                bff[nt][h] = *(const bf16x8*)&Bs[cur][row * 64 + cc * 8];
            }
        }
        #pragma unroll
        for (int mt = 0; mt < MT; ++mt)
            #pragma unroll
            for (int nt = 0; nt < 4; ++nt) {
                acc[mt][nt] = __builtin_amdgcn_mfma_f32_16x16x32_bf16(af[mt][0], bff[nt][0], acc[mt][nt], 0, 0, 0);
                acc[mt][nt] = __builtin_amdgcn_mfma_f32_16x16x32_bf16(af[mt][1], bff[nt][1], acc[mt][nt], 0, 0, 0);
            }
    }

    if (RESID_F32) {
        float* out = (float*)outv + (size_t)b * oStride;
        const float* res = resid + (size_t)b * oStride;
        #pragma unroll
        for (int mt = 0; mt < MT; ++mt)
            #pragma unroll
            for (int r = 0; r < 4; ++r) {
                int row = bm + wm + mt * 16 + quad * 4 + r;
                float bv = bias[row];
                #pragma unroll
                for (int nt = 0; nt < 4; ++nt) {
                    int col = bn + wn + nt * 16 + ln;
                    size_t idx = (size_t)row * oN + col;
                    out[idx] = acc[mt][nt][r] + bv + res[idx];
                }
            }
    } else {
        __bf16* out = (__bf16*)outv + (size_t)b * oStride;
        float bcol[4], scol[4];
        if (BIAS_COL) {
            #pragma unroll
            for (int nt = 0; nt < 4; ++nt) {
                int col = bn + wn + nt * 16 + ln;
                bcol[nt] = bias[col];
                scol[nt] = (col < loCols) ? scaleLo : 1.0f;
            }
        }
        #pragma unroll
        for (int mt = 0; mt < MT; ++mt)
            #pragma unroll
            for (int r = 0; r < 4; ++r) {
                int row = bm + wm + mt * 16 + quad * 4 + r;
                float brow = BIAS_COL ? 0.f : bias[row];
                #pragma unroll
                for (int nt = 0; nt < 4; ++nt) {
                    int col = bn + wn + nt * 16 + ln;
                    float v = BIAS_COL ? (acc[mt][nt][r] + bcol[nt]) * scol[nt]
                                       : acc[mt][nt][r] + brow;
                    out[(size_t)row * oN + col] = (__bf16)v;
                }
            }
    }
}

// ---------------- Flash attention, K-split x2, double-buffered K/V staging ----------------
__global__ __launch_bounds__(256) void attn_mfma(const __bf16* __restrict__ qkT,
                                                 const __bf16* __restrict__ vbuf,
                                                 __bf16* __restrict__ Opart,
                                                 float* __restrict__ lpart) {
    __shared__ __align__(16) __bf16 Ks[2][64 * 64];
    __shared__ __align__(16) __bf16 Vs[2][64 * 64];
    int tid = threadIdx.x;
    int wv = tid >> 6, lane = tid & 63, ln = lane & 15, quad = lane >> 4;
    int bh = blockIdx.y;
    int b = bh >> 3, h = bh & 7;
    int ks = blockIdx.z;
    int i0 = blockIdx.x * 128 + wv * 32;

    const __bf16* qbase = qkT + ((size_t)b * HW + i0 + ln) * 1024 + h * HD + quad * 8;
    bf16x8 qf[2][2];
    #pragma unroll
    for (int mt = 0; mt < 2; ++mt) {
        qf[mt][0] = *(const bf16x8*)(qbase + (size_t)mt * 16 * 1024);
        qf[mt][1] = *(const bf16x8*)(qbase + (size_t)mt * 16 * 1024 + 32);
    }

    auto stage = [&](int kb, int bu) {
        #pragma unroll
        for (int u = 0; u < 2; ++u) {
            int idx = u * 256 + tid;
            int r = idx >> 3, lc = idx & 7;
            int cg = lc ^ (r & 7);
            async16(qkT + ((size_t)b * HW + kb + r) * 1024 + 512 + h * HD + cg * 8,
                    &Ks[bu][idx * 8]);
            async16(vbuf + ((size_t)b * Cc + h * HD + r) * HW + kb + cg * 8,
                    &Vs[bu][idx * 8]);
        }
    };

    f32x4 oacc[2][4];
    #pragma unroll
    for (int mt = 0; mt < 2; ++mt)
        #pragma unroll
        for (int ct = 0; ct < 4; ++ct) oacc[mt][ct] = (f32x4){0.f, 0.f, 0.f, 0.f};
    float lsum[2] = {0.f, 0.f};

    stage(ks * 512, 0);
    for (int t = 0; t < 8; ++t) {
        int cur = t & 1;
        int kb = ks * 512 + t * 64;
        __syncthreads();                         // buf[cur] ready
        if (t < 7) stage(kb + 64, cur ^ 1);      // prefetch next tile

        f32x4 st[2][4];
        #pragma unroll
        for (int jt = 0; jt < 4; ++jt) {
            int row = jt * 16 + ln;
            int c0 = quad ^ (ln & 7);
            int c1 = (4 + quad) ^ (ln & 7);
            bf16x8 kf0 = *(const bf16x8*)&Ks[cur][row * 64 + c0 * 8];
            bf16x8 kf1 = *(const bf16x8*)&Ks[cur][row * 64 + c1 * 8];
            #pragma unroll
            for (int mt = 0; mt < 2; ++mt) {
                f32x4 s = (f32x4){0.f, 0.f, 0.f, 0.f};
                s = __builtin_amdgcn_mfma_f32_16x16x32_bf16(kf0, qf[mt][0], s, 0, 0, 0);
                s = __builtin_amdgcn_mfma_f32_16x16x32_bf16(kf1, qf[mt][1], s, 0, 0, 0);
                st[mt][jt] = s;
            }
        }

        bf16x4 pk[2][4];
        #pragma unroll
        for (int mt = 0; mt < 2; ++mt)
            #pragma unroll
            for (int jt = 0; jt < 4; ++jt) {
                float p0 = exp2f(st[mt][jt][0]);
                float p1 = exp2f(st[mt][jt][1]);
                float p2 = exp2f(st[mt][jt][2]);
                float p3 = exp2f(st[mt][jt][3]);
                lsum[mt] += (p0 + p1) + (p2 + p3);
                pk[mt][jt] = (bf16x4){(__bf16)p0, (__bf16)p1, (__bf16)p2, (__bf16)p3};
            }

        #pragma unroll
        for (int ct = 0; ct < 4; ++ct) {
            int row = ct * 16 + ln;
            bf16x4 vf[4];
            #pragma unroll
            for (int kss = 0; kss < 4; ++kss) {
                int cc16 = (kss * 2 + (quad >> 1)) ^ (ln & 7);
                vf[kss] = *(const bf16x4*)&Vs[cur][row * 64 + cc16 * 8 + (quad & 1) * 4];
            }
            #pragma unroll
            for (int mt = 0; mt < 2; ++mt)
                #pragma unroll
                for (int kss = 0; kss < 4; ++kss)
                    oacc[mt][ct] = mfma16(vf[kss], pk[mt][kss], oacc[mt][ct]);
        }
    }

    #pragma unroll
    for (int mt = 0; mt < 2; ++mt) {
        lsum[mt] += __shfl_xor(lsum[mt], 16);
        lsum[mt] += __shfl_xor(lsum[mt], 32);
        if (lane < 16)
            lpart[(size_t)ks * 65536 + (size_t)bh * 1024 + i0 + mt * 16 + lane] = lsum[mt];
        __bf16* op = Opart + (size_t)ks * 4194304 +
                     ((size_t)b * HW + i0 + mt * 16 + ln) * Cc + h * HD + quad * 4;
        #pragma unroll
        for (int ct = 0; ct < 4; ++ct) {
            bf16x4 o = { (__bf16)oacc[mt][ct][0], (__bf16)oacc[mt][ct][1],
                         (__bf16)oacc[mt][ct][2], (__bf16)oacc[mt][ct][3] };
            *(bf16x4*)(op + ct * 16) = o;
        }
    }
}

// ---------------- Combine split-K partials: attnT = (O0+O1)/(l0+l1) ----------------
__global__ __launch_bounds__(256) void attn_combine(const __bf16* __restrict__ Opart,
                                                    const float* __restrict__ lpart,
                                                    __bf16* __restrict__ attnT) {
    int gid = blockIdx.x * 256 + threadIdx.x;
    size_t base = (size_t)gid * 8;
    int b = gid >> 16;
    int rem = gid & 65535;
    int n = rem >> 6;
    int h = (rem & 63) >> 3;
    float l0 = lpart[((size_t)b * 8 + h) * 1024 + n];
    float l1 = lpart[65536 + ((size_t)b * 8 + h) * 1024 + n];
    float rl = 1.f / (l0 + l1);
    bf16x8 p0 = *(const bf16x8*)(Opart + base);
    bf16x8 p1 = *(const bf16x8*)(Opart + 4194304 + base);
    bf16x8 o;
    #pragma unroll
    for (int t = 0; t < 8; ++t)
        o[t] = (__bf16)(((float)p0[t] + (float)p1[t]) * rl);
    *(bf16x8*)(attnT + base) = o;
}

extern "C" void kernel_launch(void* const* d_in, const int* in_sizes, int n_in,
                              void* d_out, int out_size, void* d_ws, size_t ws_size,
                              hipStream_t stream) {
    const float* x      = (const float*)d_in[0];
    const float* gamma  = (const float*)d_in[1];
    const float* beta   = (const float*)d_in[2];
    const float* w_qkv  = (const float*)d_in[3];
    const float* b_qkv  = (const float*)d_in[4];
    const float* w_proj = (const float*)d_in[5];
    const float* b_proj = (const float*)d_in[6];
    float* out = (float*)d_out;

    __bf16* wq_bf  = (__bf16*)d_ws;
    __bf16* wp_bf  = wq_bf + (size_t)1536 * 512;
    __bf16* hnT    = wp_bf + (size_t)512 * 512;
    __bf16* qkT    = hnT + (size_t)Bn * HW * Cc;
    __bf16* vbuf   = qkT + (size_t)Bn * HW * 1024;
    __bf16* attnT  = vbuf + (size_t)Bn * Cc * HW;
    __bf16* Opart  = attnT + (size_t)Bn * HW * Cc;
    float*  lpart  = (float*)(Opart + (size_t)2 * Bn * HW * Cc);
    float*  gstats = lpart + 131072;

    conv_kernel<<<1024, 256, 0, stream>>>(w_qkv, wq_bf, 196608, w_proj, wp_bf, 65536);

    gn_stats<<<Bn * GROUPS, 256, 0, stream>>>(x, gstats);
    dim3 gga(32, Bn);
    gn_apply<<<gga, 256, 0, stream>>>(x, gamma, beta, gstats, hnT);

    const float QSCALE = 0.125f * 1.44269504088896f;  // hd^-0.5 * log2(e)
    dim3 gqk(8, 16, Bn);
    gemm_mfma<2, true, false><<<gqk, 256, 0, stream>>>(
        hnT, wq_bf, b_qkv, nullptr, qkT,
        (size_t)HW * Cc, 0, (size_t)HW * 1024, 1024, QSCALE, 512);

    dim3 gv(8, 8, Bn);
    gemm_mfma<2, false, false><<<gv, 256, 0, stream>>>(
        wq_bf + (size_t)1024 * 512, hnT, b_qkv + 1024, nullptr, vbuf,
        0, (size_t)HW * Cc, (size_t)Cc * HW, 1024, 1.0f, 0);

    dim3 ga(8, 64, 2);
    attn_mfma<<<ga, 256, 0, stream>>>(qkT, vbuf, Opart, lpart);
    attn_combine<<<2048, 256, 0, stream>>>(Opart, lpart, attnT);

    dim3 gp(8, 8, Bn);
    gemm_mfma<2, false, true><<<gp, 256, 0, stream>>>(
        wp_bf, attnT, b_proj, x, out,
        0, (size_t)HW * Cc, (size_t)Cc * HW, 1024, 1.0f, 0);
}

// Round 8
// 178.756 us; speedup vs baseline: 1.1251x; 1.1251x over previous
//
#include <hip/hip_runtime.h>
#include <math.h>

#define Bn 8
#define Cc 512
#define HW 1024
#define HEADS 8
#define HD 64
#define GROUPS 32
#define CPG 16
#define EPS 1e-5f

typedef float f32x4 __attribute__((ext_vector_type(4)));
typedef __bf16 bf16x8 __attribute__((ext_vector_type(8)));
typedef __bf16 bf16x4 __attribute__((ext_vector_type(4)));
typedef short s16x4 __attribute__((ext_vector_type(4)));

__device__ __forceinline__ void async16(const __bf16* g, __bf16* l) {
    __builtin_amdgcn_global_load_lds((const __attribute__((address_space(1))) unsigned int*)g,
                                     (__attribute__((address_space(3))) unsigned int*)l, 16, 0, 0);
}

__device__ __forceinline__ f32x4 mfma16(bf16x4 a, bf16x4 b, f32x4 c) {
    return __builtin_amdgcn_mfma_f32_16x16x16bf16_1k(
        __builtin_bit_cast(s16x4, a), __builtin_bit_cast(s16x4, b), c, 0, 0, 0);
}

// ---------------- fp32 -> bf16 weight conversion (both weights, one launch) ----------------
__global__ void conv_kernel(const float* __restrict__ a, __bf16* __restrict__ da, int na4,
                            const float* __restrict__ b, __bf16* __restrict__ db, int nb4) {
    int i = blockIdx.x * 256 + threadIdx.x;
    if (i < na4) {
        float4 v = ((const float4*)a)[i];
        bf16x4 o = { (__bf16)v.x, (__bf16)v.y, (__bf16)v.z, (__bf16)v.w };
        ((bf16x4*)da)[i] = o;
    } else {
        int j = i - na4;
        if (j < nb4) {
            float4 v = ((const float4*)b)[j];
            bf16x4 o = { (__bf16)v.x, (__bf16)v.y, (__bf16)v.z, (__bf16)v.w };
            ((bf16x4*)db)[j] = o;
        }
    }
}

// ---------------- GroupNorm stats: one block per (b, group) ----------------
__global__ __launch_bounds__(256) void gn_stats(const float* __restrict__ x,
                                                float* __restrict__ gstats) {
    int bg = blockIdx.x;
    int b = bg >> 5, g = bg & 31;
    const float* xp = x + ((size_t)b * Cc + g * CPG) * HW;
    int tid = threadIdx.x;
    float s = 0.f, ss = 0.f;
    for (int i = tid; i < CPG * HW; i += 256) {
        float v = xp[i];
        s += v; ss += v * v;
    }
    __shared__ float red0[4], red1[4];
    for (int off = 32; off > 0; off >>= 1) {
        s  += __shfl_down(s, off);
        ss += __shfl_down(ss, off);
    }
    int wave = tid >> 6, lane = tid & 63;
    if (lane == 0) { red0[wave] = s; red1[wave] = ss; }
    __syncthreads();
    if (tid == 0) {
        float S  = red0[0] + red0[1] + red0[2] + red0[3];
        float SS = red1[0] + red1[1] + red1[2] + red1[3];
        float mean = S / (float)(CPG * HW);
        float var  = SS / (float)(CPG * HW) - mean * mean;
        gstats[bg * 2]     = mean;
        gstats[bg * 2 + 1] = rsqrtf(var + EPS);
    }
}

// ---------------- GroupNorm apply -> hnT[b][n][c], fully coalesced writes ----------------
__global__ __launch_bounds__(256) void gn_apply(const float* __restrict__ x,
                                                const float* __restrict__ gamma,
                                                const float* __restrict__ beta,
                                                const float* __restrict__ gstats,
                                                __bf16* __restrict__ hnT) {
    int b = blockIdx.y, n0 = blockIdx.x * 32;
    __shared__ __align__(16) __bf16 T[32 * 520];
    __shared__ float gl[512], bl[512], sm[32], sr[32];
    int tid = threadIdx.x;
    if (tid < 32) {
        sm[tid] = gstats[(b * 32 + tid) * 2];
        sr[tid] = gstats[(b * 32 + tid) * 2 + 1];
    }
    for (int i = tid; i < 512; i += 256) { gl[i] = gamma[i]; bl[i] = beta[i]; }
    __syncthreads();
    const float* xb = x + (size_t)b * Cc * HW + n0;
    for (int i = tid; i < 16384; i += 256) {
        int c = i >> 5, n = i & 31;
        float v = xb[(size_t)c * HW + n];
        int g = c >> 4;
        T[n * 520 + c] = (__bf16)((v - sm[g]) * sr[g] * gl[c] + bl[c]);
    }
    __syncthreads();
    __bf16* hb = hnT + ((size_t)b * HW + n0) * Cc;
    for (int j = tid; j < 2048; j += 256) {
        int n = j >> 6, ch = j & 63;
        *(bf16x8*)&hb[(size_t)n * Cc + ch * 8] = *(const bf16x8*)&T[n * 520 + ch * 8];
    }
}

// ---------------- Fused QKV GEMM (QK part: y<16, V part: y>=16), single-buffer ----------------
// QK: D[n][o] = hnT[n]·wq[o] + bq[o]  (cols o<512 scaled by QSCALE) -> qkT[b][n][o]
// V:  D[vo][n] = wq[1024+vo]·hnT[n] + bq[1024+vo]                  -> vbuf[b][vo][n]
__global__ __launch_bounds__(256) void qkv_gemm(
    const __bf16* __restrict__ hnT, const __bf16* __restrict__ wq,
    const float* __restrict__ bias, __bf16* __restrict__ qkT,
    __bf16* __restrict__ vbuf, float scaleLo) {
    __shared__ __align__(16) __bf16 As[64 * 64];
    __shared__ __align__(16) __bf16 Bs[128 * 64];
    int tid = threadIdx.x;
    int wv = tid >> 6, lane = tid & 63, ln = lane & 15, quad = lane >> 4;
    int b = blockIdx.z;
    bool isQK = blockIdx.y < 16;
    int bm = (isQK ? blockIdx.y : blockIdx.y - 16) * 64;
    int bn = blockIdx.x * 128;
    const __bf16* hb = hnT + (size_t)b * HW * Cc;
    const __bf16* Pb = isQK ? hb : wq + (size_t)1024 * 512;
    const __bf16* Qb = isQK ? wq : hb;
    int wm = (wv >> 1) * 32, wn = (wv & 1) * 64;

    f32x4 acc[2][4];
    #pragma unroll
    for (int i = 0; i < 2; ++i)
        #pragma unroll
        for (int j = 0; j < 4; ++j) acc[i][j] = (f32x4){0.f, 0.f, 0.f, 0.f};

    for (int k0 = 0; k0 < 512; k0 += 64) {
        __syncthreads();
        #pragma unroll
        for (int u = 0; u < 2; ++u) {
            int idx = u * 256 + tid;
            int r = idx >> 3, lc = idx & 7;
            int cg = lc ^ (r & 7);
            async16(Pb + (size_t)(bm + r) * 512 + k0 + cg * 8, &As[r * 64 + lc * 8]);
        }
        #pragma unroll
        for (int u = 0; u < 4; ++u) {
            int idx = u * 256 + tid;
            int r = idx >> 3, lc = idx & 7;
            int cg = lc ^ (r & 7);
            async16(Qb + (size_t)(bn + r) * 512 + k0 + cg * 8, &Bs[r * 64 + lc * 8]);
        }
        __syncthreads();
        bf16x8 af[2][2], bff[4][2];
        #pragma unroll
        for (int mt = 0; mt < 2; ++mt) {
            int row = wm + mt * 16 + ln;
            #pragma unroll
            for (int h = 0; h < 2; ++h) {
                int cc = (h * 4 + quad) ^ (ln & 7);
                af[mt][h] = *(const bf16x8*)&As[row * 64 + cc * 8];
            }
        }
        #pragma unroll
        for (int nt = 0; nt < 4; ++nt) {
            int row = wn + nt * 16 + ln;
            #pragma unroll
            for (int h = 0; h < 2; ++h) {
                int cc = (h * 4 + quad) ^ (ln & 7);
                bff[nt][h] = *(const bf16x8*)&Bs[row * 64 + cc * 8];
            }
        }
        #pragma unroll
        for (int mt = 0; mt < 2; ++mt)
            #pragma unroll
            for (int nt = 0; nt < 4; ++nt) {
                acc[mt][nt] = __builtin_amdgcn_mfma_f32_16x16x32_bf16(af[mt][0], bff[nt][0], acc[mt][nt], 0, 0, 0);
                acc[mt][nt] = __builtin_amdgcn_mfma_f32_16x16x32_bf16(af[mt][1], bff[nt][1], acc[mt][nt], 0, 0, 0);
            }
    }

    if (isQK) {
        __bf16* out = qkT + (size_t)b * HW * 1024;
        float bcol[4], scol[4];
        #pragma unroll
        for (int nt = 0; nt < 4; ++nt) {
            int col = bn + wn + nt * 16 + ln;
            bcol[nt] = bias[col];
            scol[nt] = (col < 512) ? scaleLo : 1.0f;
        }
        #pragma unroll
        for (int mt = 0; mt < 2; ++mt)
            #pragma unroll
            for (int r = 0; r < 4; ++r) {
                int row = bm + wm + mt * 16 + quad * 4 + r;
                #pragma unroll
                for (int nt = 0; nt < 4; ++nt) {
                    int col = bn + wn + nt * 16 + ln;
                    out[(size_t)row * 1024 + col] = (__bf16)((acc[mt][nt][r] + bcol[nt]) * scol[nt]);
                }
            }
    } else {
        __bf16* out = vbuf + (size_t)b * Cc * HW;
        #pragma unroll
        for (int mt = 0; mt < 2; ++mt)
            #pragma unroll
            for (int r = 0; r < 4; ++r) {
                int row = bm + wm + mt * 16 + quad * 4 + r;
                float brow = bias[1024 + row];
                #pragma unroll
                for (int nt = 0; nt < 4; ++nt) {
                    int col = bn + wn + nt * 16 + ln;
                    out[(size_t)row * 1024 + col] = (__bf16)(acc[mt][nt][r] + brow);
                }
            }
    }
}

// ---------------- proj GEMM with fp32 residual epilogue ----------------
__global__ __launch_bounds__(256) void proj_gemm(
    const __bf16* __restrict__ wp, const __bf16* __restrict__ attnT,
    const float* __restrict__ bias, const float* __restrict__ resid,
    float* __restrict__ outp) {
    __shared__ __align__(16) __bf16 As[64 * 64];
    __shared__ __align__(16) __bf16 Bs[128 * 64];
    int tid = threadIdx.x;
    int wv = tid >> 6, lane = tid & 63, ln = lane & 15, quad = lane >> 4;
    int b = blockIdx.z;
    int bm = blockIdx.y * 64, bn = blockIdx.x * 128;
    const __bf16* Pb = wp;
    const __bf16* Qb = attnT + (size_t)b * HW * Cc;
    int wm = (wv >> 1) * 32, wn = (wv & 1) * 64;

    f32x4 acc[2][4];
    #pragma unroll
    for (int i = 0; i < 2; ++i)
        #pragma unroll
        for (int j = 0; j < 4; ++j) acc[i][j] = (f32x4){0.f, 0.f, 0.f, 0.f};

    for (int k0 = 0; k0 < 512; k0 += 64) {
        __syncthreads();
        #pragma unroll
        for (int u = 0; u < 2; ++u) {
            int idx = u * 256 + tid;
            int r = idx >> 3, lc = idx & 7;
            int cg = lc ^ (r & 7);
            async16(Pb + (size_t)(bm + r) * 512 + k0 + cg * 8, &As[r * 64 + lc * 8]);
        }
        #pragma unroll
        for (int u = 0; u < 4; ++u) {
            int idx = u * 256 + tid;
            int r = idx >> 3, lc = idx & 7;
            int cg = lc ^ (r & 7);
            async16(Qb + (size_t)(bn + r) * 512 + k0 + cg * 8, &Bs[r * 64 + lc * 8]);
        }
        __syncthreads();
        bf16x8 af[2][2], bff[4][2];
        #pragma unroll
        for (int mt = 0; mt < 2; ++mt) {
            int row = wm + mt * 16 + ln;
            #pragma unroll
            for (int h = 0; h < 2; ++h) {
                int cc = (h * 4 + quad) ^ (ln & 7);
                af[mt][h] = *(const bf16x8*)&As[row * 64 + cc * 8];
            }
        }
        #pragma unroll
        for (int nt = 0; nt < 4; ++nt) {
            int row = wn + nt * 16 + ln;
            #pragma unroll
            for (int h = 0; h < 2; ++h) {
                int cc = (h * 4 + quad) ^ (ln & 7);
                bff[nt][h] = *(const bf16x8*)&Bs[row * 64 + cc * 8];
            }
        }
        #pragma unroll
        for (int mt = 0; mt < 2; ++mt)
            #pragma unroll
            for (int nt = 0; nt < 4; ++nt) {
                acc[mt][nt] = __builtin_amdgcn_mfma_f32_16x16x32_bf16(af[mt][0], bff[nt][0], acc[mt][nt], 0, 0, 0);
                acc[mt][nt] = __builtin_amdgcn_mfma_f32_16x16x32_bf16(af[mt][1], bff[nt][1], acc[mt][nt], 0, 0, 0);
            }
    }

    float* out = outp + (size_t)b * Cc * HW;
    const float* res = resid + (size_t)b * Cc * HW;
    #pragma unroll
    for (int mt = 0; mt < 2; ++mt)
        #pragma unroll
        for (int r = 0; r < 4; ++r) {
            int row = bm + wm + mt * 16 + quad * 4 + r;
            float bv = bias[row];
            #pragma unroll
            for (int nt = 0; nt < 4; ++nt) {
                int col = bn + wn + nt * 16 + ln;
                size_t idx = (size_t)row * 1024 + col;
                out[idx] = acc[mt][nt][r] + bv + res[idx];
            }
        }
}

// ---------------- Flash attention: 512-thr blocks, XCD-local heads ----------------
// Grid (h=8, qb=4, b=8): linear idx % 8 == h -> all blocks of one head share an XCD L2.
// Block: 8 waves x 32 queries = 256 queries; K/V staged once per tile for all 8 waves.
// Max-free softmax (Q pre-scaled by 0.125*log2e), S^T trick, P stays in registers.
__global__ __launch_bounds__(512) void attn_mfma(const __bf16* __restrict__ qkT,
                                                 const __bf16* __restrict__ vbuf,
                                                 __bf16* __restrict__ attnT) {
    __shared__ __align__(16) __bf16 Ks[64 * 64];
    __shared__ __align__(16) __bf16 Vs[64 * 64];
    int tid = threadIdx.x;
    int wv = tid >> 6, lane = tid & 63, ln = lane & 15, quad = lane >> 4;
    int h = blockIdx.x, b = blockIdx.z;
    int i0 = blockIdx.y * 256 + wv * 32;

    const __bf16* qbase = qkT + ((size_t)b * HW + i0 + ln) * 1024 + h * HD + quad * 8;
    bf16x8 qf[2][2];
    #pragma unroll
    for (int mt = 0; mt < 2; ++mt) {
        qf[mt][0] = *(const bf16x8*)(qbase + (size_t)mt * 16 * 1024);
        qf[mt][1] = *(const bf16x8*)(qbase + (size_t)mt * 16 * 1024 + 32);
    }

    f32x4 oacc[2][4];
    #pragma unroll
    for (int mt = 0; mt < 2; ++mt)
        #pragma unroll
        for (int ct = 0; ct < 4; ++ct) oacc[mt][ct] = (f32x4){0.f, 0.f, 0.f, 0.f};
    float lsum[2] = {0.f, 0.f};

    int sr = tid >> 3, slc = tid & 7;
    int scg = slc ^ (sr & 7);
    const __bf16* kgp = qkT + ((size_t)b * HW + sr) * 1024 + 512 + h * HD + scg * 8;
    const __bf16* vgp = vbuf + ((size_t)b * Cc + h * HD + sr) * HW + scg * 8;

    for (int kt = 0; kt < 16; ++kt) {
        int kb = kt * 64;
        __syncthreads();
        async16(kgp + (size_t)kb * 1024, &Ks[tid * 8]);
        async16(vgp + kb, &Vs[tid * 8]);
        __syncthreads();

        f32x4 st[2][4];
        #pragma unroll
        for (int jt = 0; jt < 4; ++jt) {
            int row = jt * 16 + ln;
            int c0 = quad ^ (ln & 7);
            int c1 = (4 + quad) ^ (ln & 7);
            bf16x8 kf0 = *(const bf16x8*)&Ks[row * 64 + c0 * 8];
            bf16x8 kf1 = *(const bf16x8*)&Ks[row * 64 + c1 * 8];
            #pragma unroll
            for (int mt = 0; mt < 2; ++mt) {
                f32x4 s = (f32x4){0.f, 0.f, 0.f, 0.f};
                s = __builtin_amdgcn_mfma_f32_16x16x32_bf16(kf0, qf[mt][0], s, 0, 0, 0);
                s = __builtin_amdgcn_mfma_f32_16x16x32_bf16(kf1, qf[mt][1], s, 0, 0, 0);
                st[mt][jt] = s;
            }
        }

        bf16x4 pk[2][4];
        #pragma unroll
        for (int mt = 0; mt < 2; ++mt)
            #pragma unroll
            for (int jt = 0; jt < 4; ++jt) {
                float p0 = exp2f(st[mt][jt][0]);
                float p1 = exp2f(st[mt][jt][1]);
                float p2 = exp2f(st[mt][jt][2]);
                float p3 = exp2f(st[mt][jt][3]);
                lsum[mt] += (p0 + p1) + (p2 + p3);
                pk[mt][jt] = (bf16x4){(__bf16)p0, (__bf16)p1, (__bf16)p2, (__bf16)p3};
            }

        #pragma unroll
        for (int ct = 0; ct < 4; ++ct) {
            int row = ct * 16 + ln;
            bf16x4 vf[4];
            #pragma unroll
            for (int kss = 0; kss < 4; ++kss) {
                int cc16 = (kss * 2 + (quad >> 1)) ^ (ln & 7);
                vf[kss] = *(const bf16x4*)&Vs[row * 64 + cc16 * 8 + (quad & 1) * 4];
            }
            #pragma unroll
            for (int mt = 0; mt < 2; ++mt)
                #pragma unroll
                for (int kss = 0; kss < 4; ++kss)
                    oacc[mt][ct] = mfma16(vf[kss], pk[mt][kss], oacc[mt][ct]);
        }
    }

    #pragma unroll
    for (int mt = 0; mt < 2; ++mt) {
        lsum[mt] += __shfl_xor(lsum[mt], 16);
        lsum[mt] += __shfl_xor(lsum[mt], 32);
        float rl = 1.f / lsum[mt];
        __bf16* op = attnT + ((size_t)b * HW + i0 + mt * 16 + ln) * Cc + h * HD + quad * 4;
        #pragma unroll
        for (int ct = 0; ct < 4; ++ct) {
            bf16x4 o = { (__bf16)(oacc[mt][ct][0] * rl), (__bf16)(oacc[mt][ct][1] * rl),
                         (__bf16)(oacc[mt][ct][2] * rl), (__bf16)(oacc[mt][ct][3] * rl) };
            *(bf16x4*)(op + ct * 16) = o;
        }
    }
}

extern "C" void kernel_launch(void* const* d_in, const int* in_sizes, int n_in,
                              void* d_out, int out_size, void* d_ws, size_t ws_size,
                              hipStream_t stream) {
    const float* x      = (const float*)d_in[0];
    const float* gamma  = (const float*)d_in[1];
    const float* beta   = (const float*)d_in[2];
    const float* w_qkv  = (const float*)d_in[3];
    const float* b_qkv  = (const float*)d_in[4];
    const float* w_proj = (const float*)d_in[5];
    const float* b_proj = (const float*)d_in[6];
    float* out = (float*)d_out;

    __bf16* wq_bf  = (__bf16*)d_ws;
    __bf16* wp_bf  = wq_bf + (size_t)1536 * 512;
    __bf16* hnT    = wp_bf + (size_t)512 * 512;
    __bf16* qkT    = hnT + (size_t)Bn * HW * Cc;
    __bf16* vbuf   = qkT + (size_t)Bn * HW * 1024;
    __bf16* attnT  = vbuf + (size_t)Bn * Cc * HW;
    float*  gstats = (float*)(attnT + (size_t)Bn * HW * Cc);

    conv_kernel<<<1024, 256, 0, stream>>>(w_qkv, wq_bf, 196608, w_proj, wp_bf, 65536);

    gn_stats<<<Bn * GROUPS, 256, 0, stream>>>(x, gstats);
    dim3 gga(32, Bn);
    gn_apply<<<gga, 256, 0, stream>>>(x, gamma, beta, gstats, hnT);

    const float QSCALE = 0.125f * 1.44269504088896f;  // hd^-0.5 * log2(e)
    dim3 gqkv(8, 24, Bn);
    qkv_gemm<<<gqkv, 256, 0, stream>>>(hnT, wq_bf, b_qkv, qkT, vbuf, QSCALE);

    dim3 ga(8, 4, 8);   // (h, qb, b): idx%8 == h -> per-head XCD locality
    attn_mfma<<<ga, 512, 0, stream>>>(qkT, vbuf, attnT);

    dim3 gp(8, 8, Bn);
    proj_gemm<<<gp, 256, 0, stream>>>(wp_bf, attnT, b_proj, x, out);
}

// Round 9
// 172.487 us; speedup vs baseline: 1.1660x; 1.0363x over previous
//
#include <hip/hip_runtime.h>
#include <math.h>

#define Bn 8
#define Cc 512
#define HW 1024
#define HEADS 8
#define HD 64
#define GROUPS 32
#define CPG 16
#define EPS 1e-5f

typedef float f32x4 __attribute__((ext_vector_type(4)));
typedef __bf16 bf16x8 __attribute__((ext_vector_type(8)));
typedef __bf16 bf16x4 __attribute__((ext_vector_type(4)));
typedef short s16x4 __attribute__((ext_vector_type(4)));
typedef unsigned u32x2 __attribute__((ext_vector_type(2)));

__device__ __forceinline__ void async16(const __bf16* g, __bf16* l) {
    __builtin_amdgcn_global_load_lds((const __attribute__((address_space(1))) unsigned int*)g,
                                     (__attribute__((address_space(3))) unsigned int*)l, 16, 0, 0);
}

__device__ __forceinline__ f32x4 mfma16(bf16x4 a, bf16x4 b, f32x4 c) {
    return __builtin_amdgcn_mfma_f32_16x16x16bf16_1k(
        __builtin_bit_cast(s16x4, a), __builtin_bit_cast(s16x4, b), c, 0, 0, 0);
}

// pack hi16(f1):hi16(f0) via v_perm (bf16 truncation; p in [0,1], bias cancels in softmax)
__device__ __forceinline__ unsigned pk_bf16(float f1, float f0) {
    return __builtin_amdgcn_perm(__builtin_bit_cast(unsigned, f1),
                                 __builtin_bit_cast(unsigned, f0), 0x07060302u);
}

// ---------------- fp32 -> bf16 weight conversion (both weights, one launch) ----------------
__global__ void conv_kernel(const float* __restrict__ a, __bf16* __restrict__ da, int na4,
                            const float* __restrict__ b, __bf16* __restrict__ db, int nb4) {
    int i = blockIdx.x * 256 + threadIdx.x;
    if (i < na4) {
        float4 v = ((const float4*)a)[i];
        bf16x4 o = { (__bf16)v.x, (__bf16)v.y, (__bf16)v.z, (__bf16)v.w };
        ((bf16x4*)da)[i] = o;
    } else {
        int j = i - na4;
        if (j < nb4) {
            float4 v = ((const float4*)b)[j];
            bf16x4 o = { (__bf16)v.x, (__bf16)v.y, (__bf16)v.z, (__bf16)v.w };
            ((bf16x4*)db)[j] = o;
        }
    }
}

// ---------------- GroupNorm stats: one block per (b, group) ----------------
__global__ __launch_bounds__(256) void gn_stats(const float* __restrict__ x,
                                                float* __restrict__ gstats) {
    int bg = blockIdx.x;
    int b = bg >> 5, g = bg & 31;
    const float* xp = x + ((size_t)b * Cc + g * CPG) * HW;
    int tid = threadIdx.x;
    float s = 0.f, ss = 0.f;
    for (int i = tid; i < CPG * HW; i += 256) {
        float v = xp[i];
        s += v; ss += v * v;
    }
    __shared__ float red0[4], red1[4];
    for (int off = 32; off > 0; off >>= 1) {
        s  += __shfl_down(s, off);
        ss += __shfl_down(ss, off);
    }
    int wave = tid >> 6, lane = tid & 63;
    if (lane == 0) { red0[wave] = s; red1[wave] = ss; }
    __syncthreads();
    if (tid == 0) {
        float S  = red0[0] + red0[1] + red0[2] + red0[3];
        float SS = red1[0] + red1[1] + red1[2] + red1[3];
        float mean = S / (float)(CPG * HW);
        float var  = SS / (float)(CPG * HW) - mean * mean;
        gstats[bg * 2]     = mean;
        gstats[bg * 2 + 1] = rsqrtf(var + EPS);
    }
}

// ---------------- GroupNorm apply -> hnT[b][n][c], fully coalesced writes ----------------
__global__ __launch_bounds__(256) void gn_apply(const float* __restrict__ x,
                                                const float* __restrict__ gamma,
                                                const float* __restrict__ beta,
                                                const float* __restrict__ gstats,
                                                __bf16* __restrict__ hnT) {
    int b = blockIdx.y, n0 = blockIdx.x * 32;
    __shared__ __align__(16) __bf16 T[32 * 520];
    __shared__ float gl[512], bl[512], sm[32], sr[32];
    int tid = threadIdx.x;
    if (tid < 32) {
        sm[tid] = gstats[(b * 32 + tid) * 2];
        sr[tid] = gstats[(b * 32 + tid) * 2 + 1];
    }
    for (int i = tid; i < 512; i += 256) { gl[i] = gamma[i]; bl[i] = beta[i]; }
    __syncthreads();
    const float* xb = x + (size_t)b * Cc * HW + n0;
    for (int i = tid; i < 16384; i += 256) {
        int c = i >> 5, n = i & 31;
        float v = xb[(size_t)c * HW + n];
        int g = c >> 4;
        T[n * 520 + c] = (__bf16)((v - sm[g]) * sr[g] * gl[c] + bl[c]);
    }
    __syncthreads();
    __bf16* hb = hnT + ((size_t)b * HW + n0) * Cc;
    for (int j = tid; j < 2048; j += 256) {
        int n = j >> 6, ch = j & 63;
        *(bf16x8*)&hb[(size_t)n * Cc + ch * 8] = *(const bf16x8*)&T[n * 520 + ch * 8];
    }
}

// ---------------- Fused QKV GEMM (QK part: y<16, V part: y>=16), single-buffer ----------------
__global__ __launch_bounds__(256) void qkv_gemm(
    const __bf16* __restrict__ hnT, const __bf16* __restrict__ wq,
    const float* __restrict__ bias, __bf16* __restrict__ qkT,
    __bf16* __restrict__ vbuf, float scaleLo) {
    __shared__ __align__(16) __bf16 As[64 * 64];
    __shared__ __align__(16) __bf16 Bs[128 * 64];
    int tid = threadIdx.x;
    int wv = tid >> 6, lane = tid & 63, ln = lane & 15, quad = lane >> 4;
    int b = blockIdx.z;
    bool isQK = blockIdx.y < 16;
    int bm = (isQK ? blockIdx.y : blockIdx.y - 16) * 64;
    int bn = blockIdx.x * 128;
    const __bf16* hb = hnT + (size_t)b * HW * Cc;
    const __bf16* Pb = isQK ? hb : wq + (size_t)1024 * 512;
    const __bf16* Qb = isQK ? wq : hb;
    int wm = (wv >> 1) * 32, wn = (wv & 1) * 64;

    f32x4 acc[2][4];
    #pragma unroll
    for (int i = 0; i < 2; ++i)
        #pragma unroll
        for (int j = 0; j < 4; ++j) acc[i][j] = (f32x4){0.f, 0.f, 0.f, 0.f};

    for (int k0 = 0; k0 < 512; k0 += 64) {
        __syncthreads();
        #pragma unroll
        for (int u = 0; u < 2; ++u) {
            int idx = u * 256 + tid;
            int r = idx >> 3, lc = idx & 7;
            int cg = lc ^ (r & 7);
            async16(Pb + (size_t)(bm + r) * 512 + k0 + cg * 8, &As[r * 64 + lc * 8]);
        }
        #pragma unroll
        for (int u = 0; u < 4; ++u) {
            int idx = u * 256 + tid;
            int r = idx >> 3, lc = idx & 7;
            int cg = lc ^ (r & 7);
            async16(Qb + (size_t)(bn + r) * 512 + k0 + cg * 8, &Bs[r * 64 + lc * 8]);
        }
        __syncthreads();
        bf16x8 af[2][2], bff[4][2];
        #pragma unroll
        for (int mt = 0; mt < 2; ++mt) {
            int row = wm + mt * 16 + ln;
            #pragma unroll
            for (int h = 0; h < 2; ++h) {
                int cc = (h * 4 + quad) ^ (ln & 7);
                af[mt][h] = *(const bf16x8*)&As[row * 64 + cc * 8];
            }
        }
        #pragma unroll
        for (int nt = 0; nt < 4; ++nt) {
            int row = wn + nt * 16 + ln;
            #pragma unroll
            for (int h = 0; h < 2; ++h) {
                int cc = (h * 4 + quad) ^ (ln & 7);
                bff[nt][h] = *(const bf16x8*)&Bs[row * 64 + cc * 8];
            }
        }
        #pragma unroll
        for (int mt = 0; mt < 2; ++mt)
            #pragma unroll
            for (int nt = 0; nt < 4; ++nt) {
                acc[mt][nt] = __builtin_amdgcn_mfma_f32_16x16x32_bf16(af[mt][0], bff[nt][0], acc[mt][nt], 0, 0, 0);
                acc[mt][nt] = __builtin_amdgcn_mfma_f32_16x16x32_bf16(af[mt][1], bff[nt][1], acc[mt][nt], 0, 0, 0);
            }
    }

    if (isQK) {
        __bf16* out = qkT + (size_t)b * HW * 1024;
        float bcol[4], scol[4];
        #pragma unroll
        for (int nt = 0; nt < 4; ++nt) {
            int col = bn + wn + nt * 16 + ln;
            bcol[nt] = bias[col];
            scol[nt] = (col < 512) ? scaleLo : 1.0f;
        }
        #pragma unroll
        for (int mt = 0; mt < 2; ++mt)
            #pragma unroll
            for (int r = 0; r < 4; ++r) {
                int row = bm + wm + mt * 16 + quad * 4 + r;
                #pragma unroll
                for (int nt = 0; nt < 4; ++nt) {
                    int col = bn + wn + nt * 16 + ln;
                    out[(size_t)row * 1024 + col] = (__bf16)((acc[mt][nt][r] + bcol[nt]) * scol[nt]);
                }
            }
    } else {
        __bf16* out = vbuf + (size_t)b * Cc * HW;
        #pragma unroll
        for (int mt = 0; mt < 2; ++mt)
            #pragma unroll
            for (int r = 0; r < 4; ++r) {
                int row = bm + wm + mt * 16 + quad * 4 + r;
                float brow = bias[1024 + row];
                #pragma unroll
                for (int nt = 0; nt < 4; ++nt) {
                    int col = bn + wn + nt * 16 + ln;
                    out[(size_t)row * 1024 + col] = (__bf16)(acc[mt][nt][r] + brow);
                }
            }
    }
}

// ---------------- proj GEMM 64x64 tiles (4 blocks/CU) with fp32 residual epilogue ----------------
__global__ __launch_bounds__(256) void proj_gemm(
    const __bf16* __restrict__ wp, const __bf16* __restrict__ attnT,
    const float* __restrict__ bias, const float* __restrict__ resid,
    float* __restrict__ outp) {
    __shared__ __align__(16) __bf16 As[64 * 64];
    __shared__ __align__(16) __bf16 Bs[64 * 64];
    int tid = threadIdx.x;
    int wv = tid >> 6, lane = tid & 63, ln = lane & 15, quad = lane >> 4;
    int b = blockIdx.z;
    int bm = blockIdx.y * 64, bn = blockIdx.x * 64;
    const __bf16* Qb = attnT + (size_t)b * HW * Cc;
    int wm = (wv >> 1) * 32, wn = (wv & 1) * 32;

    f32x4 acc[2][2];
    #pragma unroll
    for (int i = 0; i < 2; ++i)
        #pragma unroll
        for (int j = 0; j < 2; ++j) acc[i][j] = (f32x4){0.f, 0.f, 0.f, 0.f};

    for (int k0 = 0; k0 < 512; k0 += 64) {
        __syncthreads();
        #pragma unroll
        for (int u = 0; u < 2; ++u) {
            int idx = u * 256 + tid;
            int r = idx >> 3, lc = idx & 7;
            int cg = lc ^ (r & 7);
            async16(wp + (size_t)(bm + r) * 512 + k0 + cg * 8, &As[r * 64 + lc * 8]);
            async16(Qb + (size_t)(bn + r) * 512 + k0 + cg * 8, &Bs[r * 64 + lc * 8]);
        }
        __syncthreads();
        bf16x8 af[2][2], bff[2][2];
        #pragma unroll
        for (int mt = 0; mt < 2; ++mt) {
            int row = wm + mt * 16 + ln;
            #pragma unroll
            for (int h = 0; h < 2; ++h) {
                int cc = (h * 4 + quad) ^ (ln & 7);
                af[mt][h] = *(const bf16x8*)&As[row * 64 + cc * 8];
            }
        }
        #pragma unroll
        for (int nt = 0; nt < 2; ++nt) {
            int row = wn + nt * 16 + ln;
            #pragma unroll
            for (int h = 0; h < 2; ++h) {
                int cc = (h * 4 + quad) ^ (ln & 7);
                bff[nt][h] = *(const bf16x8*)&Bs[row * 64 + cc * 8];
            }
        }
        #pragma unroll
        for (int mt = 0; mt < 2; ++mt)
            #pragma unroll
            for (int nt = 0; nt < 2; ++nt) {
                acc[mt][nt] = __builtin_amdgcn_mfma_f32_16x16x32_bf16(af[mt][0], bff[nt][0], acc[mt][nt], 0, 0, 0);
                acc[mt][nt] = __builtin_amdgcn_mfma_f32_16x16x32_bf16(af[mt][1], bff[nt][1], acc[mt][nt], 0, 0, 0);
            }
    }

    float* out = outp + (size_t)b * Cc * HW;
    const float* res = resid + (size_t)b * Cc * HW;
    #pragma unroll
    for (int mt = 0; mt < 2; ++mt)
        #pragma unroll
        for (int r = 0; r < 4; ++r) {
            int row = bm + wm + mt * 16 + quad * 4 + r;
            float bv = bias[row];
            #pragma unroll
            for (int nt = 0; nt < 2; ++nt) {
                int col = bn + wn + nt * 16 + ln;
                size_t idx = (size_t)row * 1024 + col;
                out[idx] = acc[mt][nt][r] + bv + res[idx];
            }
        }
}

// ---------------- Flash attention: 256-thr blocks, XCD-local heads, fast softmax VALU ----------------
// Grid (h=8, qb=8, b=8): linear idx % 8 == h -> per-head XCD L2 locality. 2 blocks/CU.
// Max-free softmax: Q pre-scaled by 0.125*log2e; p = v_exp_f32(s); P packed via v_perm.
__global__ __launch_bounds__(256) void attn_mfma(const __bf16* __restrict__ qkT,
                                                 const __bf16* __restrict__ vbuf,
                                                 __bf16* __restrict__ attnT) {
    __shared__ __align__(16) __bf16 Ks[64 * 64];
    __shared__ __align__(16) __bf16 Vs[64 * 64];
    int tid = threadIdx.x;
    int wv = tid >> 6, lane = tid & 63, ln = lane & 15, quad = lane >> 4;
    int h = blockIdx.x, b = blockIdx.z;
    int i0 = blockIdx.y * 128 + wv * 32;

    const __bf16* qbase = qkT + ((size_t)b * HW + i0 + ln) * 1024 + h * HD + quad * 8;
    bf16x8 qf[2][2];
    #pragma unroll
    for (int mt = 0; mt < 2; ++mt) {
        qf[mt][0] = *(const bf16x8*)(qbase + (size_t)mt * 16 * 1024);
        qf[mt][1] = *(const bf16x8*)(qbase + (size_t)mt * 16 * 1024 + 32);
    }

    f32x4 oacc[2][4];
    #pragma unroll
    for (int mt = 0; mt < 2; ++mt)
        #pragma unroll
        for (int ct = 0; ct < 4; ++ct) oacc[mt][ct] = (f32x4){0.f, 0.f, 0.f, 0.f};
    float lsum[2] = {0.f, 0.f};

    for (int kt = 0; kt < 16; ++kt) {
        int kb = kt * 64;
        __syncthreads();
        #pragma unroll
        for (int u = 0; u < 2; ++u) {
            int idx = u * 256 + tid;
            int r = idx >> 3, lc = idx & 7;
            int cg = lc ^ (r & 7);
            async16(qkT + ((size_t)b * HW + kb + r) * 1024 + 512 + h * HD + cg * 8,
                    &Ks[idx * 8]);
            async16(vbuf + ((size_t)b * Cc + h * HD + r) * HW + kb + cg * 8,
                    &Vs[idx * 8]);
        }
        __syncthreads();

        f32x4 st[2][4];
        #pragma unroll
        for (int jt = 0; jt < 4; ++jt) {
            int row = jt * 16 + ln;
            int c0 = quad ^ (ln & 7);
            int c1 = (4 + quad) ^ (ln & 7);
            bf16x8 kf0 = *(const bf16x8*)&Ks[row * 64 + c0 * 8];
            bf16x8 kf1 = *(const bf16x8*)&Ks[row * 64 + c1 * 8];
            #pragma unroll
            for (int mt = 0; mt < 2; ++mt) {
                f32x4 s = (f32x4){0.f, 0.f, 0.f, 0.f};
                s = __builtin_amdgcn_mfma_f32_16x16x32_bf16(kf0, qf[mt][0], s, 0, 0, 0);
                s = __builtin_amdgcn_mfma_f32_16x16x32_bf16(kf1, qf[mt][1], s, 0, 0, 0);
                st[mt][jt] = s;
            }
        }

        bf16x4 pk[2][4];
        #pragma unroll
        for (int mt = 0; mt < 2; ++mt)
            #pragma unroll
            for (int jt = 0; jt < 4; ++jt) {
                float p0 = __builtin_amdgcn_exp2f(st[mt][jt][0]);
                float p1 = __builtin_amdgcn_exp2f(st[mt][jt][1]);
                float p2 = __builtin_amdgcn_exp2f(st[mt][jt][2]);
                float p3 = __builtin_amdgcn_exp2f(st[mt][jt][3]);
                lsum[mt] += (p0 + p1) + (p2 + p3);
                u32x2 w = { pk_bf16(p1, p0), pk_bf16(p3, p2) };
                pk[mt][jt] = __builtin_bit_cast(bf16x4, w);
            }

        #pragma unroll
        for (int ct = 0; ct < 4; ++ct) {
            int row = ct * 16 + ln;
            bf16x4 vf[4];
            #pragma unroll
            for (int kss = 0; kss < 4; ++kss) {
                int cc16 = (kss * 2 + (quad >> 1)) ^ (ln & 7);
                vf[kss] = *(const bf16x4*)&Vs[row * 64 + cc16 * 8 + (quad & 1) * 4];
            }
            #pragma unroll
            for (int mt = 0; mt < 2; ++mt)
                #pragma unroll
                for (int kss = 0; kss < 4; ++kss)
                    oacc[mt][ct] = mfma16(vf[kss], pk[mt][kss], oacc[mt][ct]);
        }
    }

    #pragma unroll
    for (int mt = 0; mt < 2; ++mt) {
        lsum[mt] += __shfl_xor(lsum[mt], 16);
        lsum[mt] += __shfl_xor(lsum[mt], 32);
        float rl = 1.f / lsum[mt];
        __bf16* op = attnT + ((size_t)b * HW + i0 + mt * 16 + ln) * Cc + h * HD + quad * 4;
        #pragma unroll
        for (int ct = 0; ct < 4; ++ct) {
            bf16x4 o = { (__bf16)(oacc[mt][ct][0] * rl), (__bf16)(oacc[mt][ct][1] * rl),
                         (__bf16)(oacc[mt][ct][2] * rl), (__bf16)(oacc[mt][ct][3] * rl) };
            *(bf16x4*)(op + ct * 16) = o;
        }
    }
}

extern "C" void kernel_launch(void* const* d_in, const int* in_sizes, int n_in,
                              void* d_out, int out_size, void* d_ws, size_t ws_size,
                              hipStream_t stream) {
    const float* x      = (const float*)d_in[0];
    const float* gamma  = (const float*)d_in[1];
    const float* beta   = (const float*)d_in[2];
    const float* w_qkv  = (const float*)d_in[3];
    const float* b_qkv  = (const float*)d_in[4];
    const float* w_proj = (const float*)d_in[5];
    const float* b_proj = (const float*)d_in[6];
    float* out = (float*)d_out;

    __bf16* wq_bf  = (__bf16*)d_ws;
    __bf16* wp_bf  = wq_bf + (size_t)1536 * 512;
    __bf16* hnT    = wp_bf + (size_t)512 * 512;
    __bf16* qkT    = hnT + (size_t)Bn * HW * Cc;
    __bf16* vbuf   = qkT + (size_t)Bn * HW * 1024;
    __bf16* attnT  = vbuf + (size_t)Bn * Cc * HW;
    float*  gstats = (float*)(attnT + (size_t)Bn * HW * Cc);

    conv_kernel<<<1024, 256, 0, stream>>>(w_qkv, wq_bf, 196608, w_proj, wp_bf, 65536);

    gn_stats<<<Bn * GROUPS, 256, 0, stream>>>(x, gstats);
    dim3 gga(32, Bn);
    gn_apply<<<gga, 256, 0, stream>>>(x, gamma, beta, gstats, hnT);

    const float QSCALE = 0.125f * 1.44269504088896f;  // hd^-0.5 * log2(e)
    dim3 gqkv(8, 24, Bn);
    qkv_gemm<<<gqkv, 256, 0, stream>>>(hnT, wq_bf, b_qkv, qkT, vbuf, QSCALE);

    dim3 ga(8, 8, 8);   // (h, qb, b): idx%8 == h -> per-head XCD locality
    attn_mfma<<<ga, 256, 0, stream>>>(qkT, vbuf, attnT);

    dim3 gp(16, 8, Bn);
    proj_gemm<<<gp, 256, 0, stream>>>(wp_bf, attnT, b_proj, x, out);
}

// Round 10
// 161.077 us; speedup vs baseline: 1.2486x; 1.0708x over previous
//
#include <hip/hip_runtime.h>
#include <math.h>

#define Bn 8
#define Cc 512
#define HW 1024
#define HEADS 8
#define HD 64
#define GROUPS 32
#define CPG 16
#define EPS 1e-5f

typedef float f32x4 __attribute__((ext_vector_type(4)));
typedef __bf16 bf16x8 __attribute__((ext_vector_type(8)));
typedef __bf16 bf16x4 __attribute__((ext_vector_type(4)));
typedef short s16x4 __attribute__((ext_vector_type(4)));
typedef unsigned u32x2 __attribute__((ext_vector_type(2)));

__device__ __forceinline__ void async16(const __bf16* g, __bf16* l) {
    __builtin_amdgcn_global_load_lds((const __attribute__((address_space(1))) unsigned int*)g,
                                     (__attribute__((address_space(3))) unsigned int*)l, 16, 0, 0);
}

__device__ __forceinline__ f32x4 mfma16(bf16x4 a, bf16x4 b, f32x4 c) {
    return __builtin_amdgcn_mfma_f32_16x16x16bf16_1k(
        __builtin_bit_cast(s16x4, a), __builtin_bit_cast(s16x4, b), c, 0, 0, 0);
}

// pack hi16(f1):hi16(f0) via v_perm (bf16 truncation; p in [0,1], bias cancels in softmax)
__device__ __forceinline__ unsigned pk_bf16(float f1, float f0) {
    return __builtin_amdgcn_perm(__builtin_bit_cast(unsigned, f1),
                                 __builtin_bit_cast(unsigned, f0), 0x07060302u);
}

// ---------------- fp32 -> bf16 weight conversion (both weights, one launch) ----------------
__global__ void conv_kernel(const float* __restrict__ a, __bf16* __restrict__ da, int na4,
                            const float* __restrict__ b, __bf16* __restrict__ db, int nb4) {
    int i = blockIdx.x * 256 + threadIdx.x;
    if (i < na4) {
        float4 v = ((const float4*)a)[i];
        bf16x4 o = { (__bf16)v.x, (__bf16)v.y, (__bf16)v.z, (__bf16)v.w };
        ((bf16x4*)da)[i] = o;
    } else {
        int j = i - na4;
        if (j < nb4) {
            float4 v = ((const float4*)b)[j];
            bf16x4 o = { (__bf16)v.x, (__bf16)v.y, (__bf16)v.z, (__bf16)v.w };
            ((bf16x4*)db)[j] = o;
        }
    }
}

// ---------------- GroupNorm stats: one block per (b, group) ----------------
__global__ __launch_bounds__(256) void gn_stats(const float* __restrict__ x,
                                                float* __restrict__ gstats) {
    int bg = blockIdx.x;
    int b = bg >> 5, g = bg & 31;
    const float* xp = x + ((size_t)b * Cc + g * CPG) * HW;
    int tid = threadIdx.x;
    float s = 0.f, ss = 0.f;
    for (int i = tid; i < CPG * HW; i += 256) {
        float v = xp[i];
        s += v; ss += v * v;
    }
    __shared__ float red0[4], red1[4];
    for (int off = 32; off > 0; off >>= 1) {
        s  += __shfl_down(s, off);
        ss += __shfl_down(ss, off);
    }
    int wave = tid >> 6, lane = tid & 63;
    if (lane == 0) { red0[wave] = s; red1[wave] = ss; }
    __syncthreads();
    if (tid == 0) {
        float S  = red0[0] + red0[1] + red0[2] + red0[3];
        float SS = red1[0] + red1[1] + red1[2] + red1[3];
        float mean = S / (float)(CPG * HW);
        float var  = SS / (float)(CPG * HW) - mean * mean;
        gstats[bg * 2]     = mean;
        gstats[bg * 2 + 1] = rsqrtf(var + EPS);
    }
}

// ---------------- GroupNorm apply -> hnT[b][n][c], fully coalesced writes ----------------
__global__ __launch_bounds__(256) void gn_apply(const float* __restrict__ x,
                                                const float* __restrict__ gamma,
                                                const float* __restrict__ beta,
                                                const float* __restrict__ gstats,
                                                __bf16* __restrict__ hnT) {
    int b = blockIdx.y, n0 = blockIdx.x * 32;
    __shared__ __align__(16) __bf16 T[32 * 520];
    __shared__ float gl[512], bl[512], sm[32], sr[32];
    int tid = threadIdx.x;
    if (tid < 32) {
        sm[tid] = gstats[(b * 32 + tid) * 2];
        sr[tid] = gstats[(b * 32 + tid) * 2 + 1];
    }
    for (int i = tid; i < 512; i += 256) { gl[i] = gamma[i]; bl[i] = beta[i]; }
    __syncthreads();
    const float* xb = x + (size_t)b * Cc * HW + n0;
    for (int i = tid; i < 16384; i += 256) {
        int c = i >> 5, n = i & 31;
        float v = xb[(size_t)c * HW + n];
        int g = c >> 4;
        T[n * 520 + c] = (__bf16)((v - sm[g]) * sr[g] * gl[c] + bl[c]);
    }
    __syncthreads();
    __bf16* hb = hnT + ((size_t)b * HW + n0) * Cc;
    for (int j = tid; j < 2048; j += 256) {
        int n = j >> 6, ch = j & 63;
        *(bf16x8*)&hb[(size_t)n * Cc + ch * 8] = *(const bf16x8*)&T[n * 520 + ch * 8];
    }
}

// ---------------- Fused QKV GEMM, m97-style 128x128 tiles ----------------
// y<8: QK part D[n][o] = hnT[n]·wq[o] + bq[o] (cols<512 scaled) -> qkT
// y>=8: V part D[vo][n] = wq[1024+vo]·hnT[n] + bq[1024+vo]      -> vbuf
__global__ __launch_bounds__(256) void qkv_gemm(
    const __bf16* __restrict__ hnT, const __bf16* __restrict__ wq,
    const float* __restrict__ bias, __bf16* __restrict__ qkT,
    __bf16* __restrict__ vbuf, float scaleLo) {
    __shared__ __align__(16) __bf16 As[128 * 64];
    __shared__ __align__(16) __bf16 Bs[128 * 64];
    int tid = threadIdx.x;
    int wv = tid >> 6, lane = tid & 63, ln = lane & 15, quad = lane >> 4;
    int b = blockIdx.z;
    bool isQK = blockIdx.y < 8;
    int bm = (isQK ? blockIdx.y : blockIdx.y - 8) * 128;
    int bn = blockIdx.x * 128;
    const __bf16* hb = hnT + (size_t)b * HW * Cc;
    const __bf16* Pb = isQK ? hb : wq + (size_t)1024 * 512;
    const __bf16* Qb = isQK ? wq : hb;
    int wm = (wv >> 1) * 64, wn = (wv & 1) * 64;

    f32x4 acc[4][4];
    #pragma unroll
    for (int i = 0; i < 4; ++i)
        #pragma unroll
        for (int j = 0; j < 4; ++j) acc[i][j] = (f32x4){0.f, 0.f, 0.f, 0.f};

    for (int k0 = 0; k0 < 512; k0 += 64) {
        __syncthreads();
        #pragma unroll
        for (int u = 0; u < 4; ++u) {
            int idx = u * 256 + tid;
            int r = idx >> 3, lc = idx & 7;
            int cg = lc ^ (r & 7);
            async16(Pb + (size_t)(bm + r) * 512 + k0 + cg * 8, &As[r * 64 + lc * 8]);
            async16(Qb + (size_t)(bn + r) * 512 + k0 + cg * 8, &Bs[r * 64 + lc * 8]);
        }
        __syncthreads();
        bf16x8 af[4][2], bff[4][2];
        #pragma unroll
        for (int mt = 0; mt < 4; ++mt) {
            int row = wm + mt * 16 + ln;
            #pragma unroll
            for (int h = 0; h < 2; ++h) {
                int cc = (h * 4 + quad) ^ (ln & 7);
                af[mt][h] = *(const bf16x8*)&As[row * 64 + cc * 8];
            }
        }
        #pragma unroll
        for (int nt = 0; nt < 4; ++nt) {
            int row = wn + nt * 16 + ln;
            #pragma unroll
            for (int h = 0; h < 2; ++h) {
                int cc = (h * 4 + quad) ^ (ln & 7);
                bff[nt][h] = *(const bf16x8*)&Bs[row * 64 + cc * 8];
            }
        }
        #pragma unroll
        for (int mt = 0; mt < 4; ++mt)
            #pragma unroll
            for (int nt = 0; nt < 4; ++nt) {
                acc[mt][nt] = __builtin_amdgcn_mfma_f32_16x16x32_bf16(af[mt][0], bff[nt][0], acc[mt][nt], 0, 0, 0);
                acc[mt][nt] = __builtin_amdgcn_mfma_f32_16x16x32_bf16(af[mt][1], bff[nt][1], acc[mt][nt], 0, 0, 0);
            }
    }

    if (isQK) {
        __bf16* out = qkT + (size_t)b * HW * 1024;
        float bcol[4], scol[4];
        #pragma unroll
        for (int nt = 0; nt < 4; ++nt) {
            int col = bn + wn + nt * 16 + ln;
            bcol[nt] = bias[col];
            scol[nt] = (col < 512) ? scaleLo : 1.0f;
        }
        #pragma unroll
        for (int mt = 0; mt < 4; ++mt)
            #pragma unroll
            for (int r = 0; r < 4; ++r) {
                int row = bm + wm + mt * 16 + quad * 4 + r;
                #pragma unroll
                for (int nt = 0; nt < 4; ++nt) {
                    int col = bn + wn + nt * 16 + ln;
                    out[(size_t)row * 1024 + col] = (__bf16)((acc[mt][nt][r] + bcol[nt]) * scol[nt]);
                }
            }
    } else {
        __bf16* out = vbuf + (size_t)b * Cc * HW;
        #pragma unroll
        for (int mt = 0; mt < 4; ++mt)
            #pragma unroll
            for (int r = 0; r < 4; ++r) {
                int row = bm + wm + mt * 16 + quad * 4 + r;
                float brow = bias[1024 + row];
                #pragma unroll
                for (int nt = 0; nt < 4; ++nt) {
                    int col = bn + wn + nt * 16 + ln;
                    out[(size_t)row * 1024 + col] = (__bf16)(acc[mt][nt][r] + brow);
                }
            }
    }
}

// ---------------- proj GEMM 64x128 tiles (grid 512) with fp32 residual epilogue ----------------
__global__ __launch_bounds__(256) void proj_gemm(
    const __bf16* __restrict__ wp, const __bf16* __restrict__ attnT,
    const float* __restrict__ bias, const float* __restrict__ resid,
    float* __restrict__ outp) {
    __shared__ __align__(16) __bf16 As[64 * 64];
    __shared__ __align__(16) __bf16 Bs[128 * 64];
    int tid = threadIdx.x;
    int wv = tid >> 6, lane = tid & 63, ln = lane & 15, quad = lane >> 4;
    int b = blockIdx.z;
    int bm = blockIdx.y * 64, bn = blockIdx.x * 128;
    const __bf16* Qb = attnT + (size_t)b * HW * Cc;
    int wm = (wv >> 1) * 32, wn = (wv & 1) * 64;

    f32x4 acc[2][4];
    #pragma unroll
    for (int i = 0; i < 2; ++i)
        #pragma unroll
        for (int j = 0; j < 4; ++j) acc[i][j] = (f32x4){0.f, 0.f, 0.f, 0.f};

    for (int k0 = 0; k0 < 512; k0 += 64) {
        __syncthreads();
        #pragma unroll
        for (int u = 0; u < 2; ++u) {
            int idx = u * 256 + tid;
            int r = idx >> 3, lc = idx & 7;
            int cg = lc ^ (r & 7);
            async16(wp + (size_t)(bm + r) * 512 + k0 + cg * 8, &As[r * 64 + lc * 8]);
        }
        #pragma unroll
        for (int u = 0; u < 4; ++u) {
            int idx = u * 256 + tid;
            int r = idx >> 3, lc = idx & 7;
            int cg = lc ^ (r & 7);
            async16(Qb + (size_t)(bn + r) * 512 + k0 + cg * 8, &Bs[r * 64 + lc * 8]);
        }
        __syncthreads();
        bf16x8 af[2][2], bff[4][2];
        #pragma unroll
        for (int mt = 0; mt < 2; ++mt) {
            int row = wm + mt * 16 + ln;
            #pragma unroll
            for (int h = 0; h < 2; ++h) {
                int cc = (h * 4 + quad) ^ (ln & 7);
                af[mt][h] = *(const bf16x8*)&As[row * 64 + cc * 8];
            }
        }
        #pragma unroll
        for (int nt = 0; nt < 4; ++nt) {
            int row = wn + nt * 16 + ln;
            #pragma unroll
            for (int h = 0; h < 2; ++h) {
                int cc = (h * 4 + quad) ^ (ln & 7);
                bff[nt][h] = *(const bf16x8*)&Bs[row * 64 + cc * 8];
            }
        }
        #pragma unroll
        for (int mt = 0; mt < 2; ++mt)
            #pragma unroll
            for (int nt = 0; nt < 4; ++nt) {
                acc[mt][nt] = __builtin_amdgcn_mfma_f32_16x16x32_bf16(af[mt][0], bff[nt][0], acc[mt][nt], 0, 0, 0);
                acc[mt][nt] = __builtin_amdgcn_mfma_f32_16x16x32_bf16(af[mt][1], bff[nt][1], acc[mt][nt], 0, 0, 0);
            }
    }

    float* out = outp + (size_t)b * Cc * HW;
    const float* res = resid + (size_t)b * Cc * HW;
    #pragma unroll
    for (int mt = 0; mt < 2; ++mt)
        #pragma unroll
        for (int r = 0; r < 4; ++r) {
            int row = bm + wm + mt * 16 + quad * 4 + r;
            float bv = bias[row];
            #pragma unroll
            for (int nt = 0; nt < 4; ++nt) {
                int col = bn + wn + nt * 16 + ln;
                size_t idx = (size_t)row * 1024 + col;
                out[idx] = acc[mt][nt][r] + bv + res[idx];
            }
        }
}

// ---------------- Flash attention: 128 keys per barrier (2 x 64 sub-buffers) ----------------
// Grid (h=8, qb=8, b=8): idx%8 == h -> per-head XCD L2 locality.
// Max-free softmax: Q pre-scaled by 0.125*log2e; p = v_exp_f32(s); P packed via v_perm.
__global__ __launch_bounds__(256) void attn_mfma(const __bf16* __restrict__ qkT,
                                                 const __bf16* __restrict__ vbuf,
                                                 __bf16* __restrict__ attnT) {
    __shared__ __align__(16) __bf16 Ks[2][64 * 64];
    __shared__ __align__(16) __bf16 Vs[2][64 * 64];
    int tid = threadIdx.x;
    int wv = tid >> 6, lane = tid & 63, ln = lane & 15, quad = lane >> 4;
    int h = blockIdx.x, b = blockIdx.z;
    int i0 = blockIdx.y * 128 + wv * 32;

    const __bf16* qbase = qkT + ((size_t)b * HW + i0 + ln) * 1024 + h * HD + quad * 8;
    bf16x8 qf[2][2];
    #pragma unroll
    for (int mt = 0; mt < 2; ++mt) {
        qf[mt][0] = *(const bf16x8*)(qbase + (size_t)mt * 16 * 1024);
        qf[mt][1] = *(const bf16x8*)(qbase + (size_t)mt * 16 * 1024 + 32);
    }

    f32x4 oacc[2][4];
    #pragma unroll
    for (int mt = 0; mt < 2; ++mt)
        #pragma unroll
        for (int ct = 0; ct < 4; ++ct) oacc[mt][ct] = (f32x4){0.f, 0.f, 0.f, 0.f};
    float lsum[2] = {0.f, 0.f};

    for (int kt = 0; kt < 8; ++kt) {        // 8 barrier phases, 128 keys each
        __syncthreads();
        #pragma unroll
        for (int hh = 0; hh < 2; ++hh) {
            int kb = kt * 128 + hh * 64;
            #pragma unroll
            for (int u = 0; u < 2; ++u) {
                int idx = u * 256 + tid;
                int r = idx >> 3, lc = idx & 7;
                int cg = lc ^ (r & 7);
                async16(qkT + ((size_t)b * HW + kb + r) * 1024 + 512 + h * HD + cg * 8,
                        &Ks[hh][idx * 8]);
                async16(vbuf + ((size_t)b * Cc + h * HD + r) * HW + kb + cg * 8,
                        &Vs[hh][idx * 8]);
            }
        }
        __syncthreads();

        #pragma unroll
        for (int hh = 0; hh < 2; ++hh) {
            f32x4 st[2][4];
            #pragma unroll
            for (int jt = 0; jt < 4; ++jt) {
                int row = jt * 16 + ln;
                int c0 = quad ^ (ln & 7);
                int c1 = (4 + quad) ^ (ln & 7);
                bf16x8 kf0 = *(const bf16x8*)&Ks[hh][row * 64 + c0 * 8];
                bf16x8 kf1 = *(const bf16x8*)&Ks[hh][row * 64 + c1 * 8];
                #pragma unroll
                for (int mt = 0; mt < 2; ++mt) {
                    f32x4 s = (f32x4){0.f, 0.f, 0.f, 0.f};
                    s = __builtin_amdgcn_mfma_f32_16x16x32_bf16(kf0, qf[mt][0], s, 0, 0, 0);
                    s = __builtin_amdgcn_mfma_f32_16x16x32_bf16(kf1, qf[mt][1], s, 0, 0, 0);
                    st[mt][jt] = s;
                }
            }

            bf16x4 pk[2][4];
            #pragma unroll
            for (int mt = 0; mt < 2; ++mt)
                #pragma unroll
                for (int jt = 0; jt < 4; ++jt) {
                    float p0 = __builtin_amdgcn_exp2f(st[mt][jt][0]);
                    float p1 = __builtin_amdgcn_exp2f(st[mt][jt][1]);
                    float p2 = __builtin_amdgcn_exp2f(st[mt][jt][2]);
                    float p3 = __builtin_amdgcn_exp2f(st[mt][jt][3]);
                    lsum[mt] += (p0 + p1) + (p2 + p3);
                    u32x2 w = { pk_bf16(p1, p0), pk_bf16(p3, p2) };
                    pk[mt][jt] = __builtin_bit_cast(bf16x4, w);
                }

            #pragma unroll
            for (int ct = 0; ct < 4; ++ct) {
                int row = ct * 16 + ln;
                bf16x4 vf[4];
                #pragma unroll
                for (int kss = 0; kss < 4; ++kss) {
                    int cc16 = (kss * 2 + (quad >> 1)) ^ (ln & 7);
                    vf[kss] = *(const bf16x4*)&Vs[hh][row * 64 + cc16 * 8 + (quad & 1) * 4];
                }
                #pragma unroll
                for (int mt = 0; mt < 2; ++mt)
                    #pragma unroll
                    for (int kss = 0; kss < 4; ++kss)
                        oacc[mt][ct] = mfma16(vf[kss], pk[mt][kss], oacc[mt][ct]);
            }
        }
    }

    #pragma unroll
    for (int mt = 0; mt < 2; ++mt) {
        lsum[mt] += __shfl_xor(lsum[mt], 16);
        lsum[mt] += __shfl_xor(lsum[mt], 32);
        float rl = 1.f / lsum[mt];
        __bf16* op = attnT + ((size_t)b * HW + i0 + mt * 16 + ln) * Cc + h * HD + quad * 4;
        #pragma unroll
        for (int ct = 0; ct < 4; ++ct) {
            bf16x4 o = { (__bf16)(oacc[mt][ct][0] * rl), (__bf16)(oacc[mt][ct][1] * rl),
                         (__bf16)(oacc[mt][ct][2] * rl), (__bf16)(oacc[mt][ct][3] * rl) };
            *(bf16x4*)(op + ct * 16) = o;
        }
    }
}

extern "C" void kernel_launch(void* const* d_in, const int* in_sizes, int n_in,
                              void* d_out, int out_size, void* d_ws, size_t ws_size,
                              hipStream_t stream) {
    const float* x      = (const float*)d_in[0];
    const float* gamma  = (const float*)d_in[1];
    const float* beta   = (const float*)d_in[2];
    const float* w_qkv  = (const float*)d_in[3];
    const float* b_qkv  = (const float*)d_in[4];
    const float* w_proj = (const float*)d_in[5];
    const float* b_proj = (const float*)d_in[6];
    float* out = (float*)d_out;

    __bf16* wq_bf  = (__bf16*)d_ws;
    __bf16* wp_bf  = wq_bf + (size_t)1536 * 512;
    __bf16* hnT    = wp_bf + (size_t)512 * 512;
    __bf16* qkT    = hnT + (size_t)Bn * HW * Cc;
    __bf16* vbuf   = qkT + (size_t)Bn * HW * 1024;
    __bf16* attnT  = vbuf + (size_t)Bn * Cc * HW;
    float*  gstats = (float*)(attnT + (size_t)Bn * HW * Cc);

    conv_kernel<<<1024, 256, 0, stream>>>(w_qkv, wq_bf, 196608, w_proj, wp_bf, 65536);

    gn_stats<<<Bn * GROUPS, 256, 0, stream>>>(x, gstats);
    dim3 gga(32, Bn);
    gn_apply<<<gga, 256, 0, stream>>>(x, gamma, beta, gstats, hnT);

    const float QSCALE = 0.125f * 1.44269504088896f;  // hd^-0.5 * log2(e)
    dim3 gqkv(8, 12, Bn);   // y<8: QK 128-row tiles; y>=8: V 128-row tiles
    qkv_gemm<<<gqkv, 256, 0, stream>>>(hnT, wq_bf, b_qkv, qkT, vbuf, QSCALE);

    dim3 ga(8, 8, 8);       // (h, qb, b): idx%8 == h -> per-head XCD locality
    attn_mfma<<<ga, 256, 0, stream>>>(qkT, vbuf, attnT);

    dim3 gp(8, 8, Bn);
    proj_gemm<<<gp, 256, 0, stream>>>(wp_bf, attnT, b_proj, x, out);
}